// Round 2
// baseline (3387.111 us; speedup 1.0000x reference)
//
#include <hip/hip_runtime.h>
#include <stdint.h>

typedef unsigned int u32;

struct Ptr7 { const float* p[7]; };

// ---------------- h0 = x * node_W + node_b ----------------
__global__ void k_init_h(const float* __restrict__ x, const float* __restrict__ nW,
                         const float* __restrict__ nb, float* __restrict__ h, int total) {
    int i = blockIdx.x * 256 + threadIdx.x;
    if (i >= total) return;
    int n = i >> 6, d = i & 63;
    h[i] = x[n] * nW[d] + nb[d];
}

// ---------------- degree counts + contribution counts ----------------
__global__ void k_edge_count(const int* __restrict__ ei, const int* __restrict__ ty,
                             int E, int N, u32* __restrict__ degcnt, u32* __restrict__ cnt) {
    int e = blockIdx.x * 256 + threadIdx.x;
    if (e >= E) return;
    int s = ei[e], d = ei[E + e], t = ty[e];
    if (t >= 1) { atomicAdd(&degcnt[(t - 1) * N + d], 1u); atomicAdd(&cnt[d], 1u); }
    if (t >= 2) { atomicAdd(&degcnt[(t + 2) * N + s], 1u); atomicAdd(&cnt[s], 1u); }
}

__global__ void k_dinv(const u32* __restrict__ degcnt, float* __restrict__ dinv, int total) {
    int i = blockIdx.x * 256 + threadIdx.x;
    if (i >= total) return;
    dinv[i] = rsqrtf(1.0f + (float)degcnt[i]);
}

__global__ void k_bsum(Ptr7 b, float* __restrict__ bsum) {
    int d = threadIdx.x;
    float s = 0.f;
#pragma unroll
    for (int k = 0; k < 7; k++) s += b.p[k][d];
    bsum[d] = s;
}

// ---------------- 3-pass exclusive scan (chunk = 1024/block) ----------------
__global__ void k_scan1(const u32* __restrict__ cnt, u32* __restrict__ S, u32* __restrict__ bsums) {
    __shared__ u32 lds[256];
    int t = threadIdx.x;
    int base = blockIdx.x * 1024;
    uint4 c = *((const uint4*)(cnt + base) + t);
    u32 s0 = c.x, s1 = s0 + c.y, s2 = s1 + c.z, s3 = s2 + c.w;
    lds[t] = s3; __syncthreads();
    for (int off = 1; off < 256; off <<= 1) {
        u32 v = (t >= off) ? lds[t - off] : 0u;
        __syncthreads();
        lds[t] += v;
        __syncthreads();
    }
    u32 excl = lds[t] - s3;
    uint4 o; o.x = excl + s0; o.y = excl + s1; o.z = excl + s2; o.w = excl + s3;
    *((uint4*)(S + base) + t) = o;
    if (t == 255) bsums[blockIdx.x] = lds[255];
}

__global__ void k_scan2(const u32* __restrict__ bsums, u32* __restrict__ bexcl, int nb) {
    __shared__ u32 lds[256];
    int t = threadIdx.x;
    u32 v = (t < nb) ? bsums[t] : 0u;
    lds[t] = v; __syncthreads();
    for (int off = 1; off < 256; off <<= 1) {
        u32 x2 = (t >= off) ? lds[t - off] : 0u;
        __syncthreads();
        lds[t] += x2;
        __syncthreads();
    }
    if (t < nb) bexcl[t] = lds[t] - v;
}

__global__ void k_scan3(u32* __restrict__ S, const u32* __restrict__ cnt,
                        const u32* __restrict__ bexcl, u32* __restrict__ offsets) {
    int t = threadIdx.x;
    int base = blockIdx.x * 1024;
    u32 add = bexcl[blockIdx.x];
    uint4 s = *((const uint4*)(S + base) + t);
    uint4 c = *((const uint4*)(cnt + base) + t);
    int i0 = base + t * 4;
    u32 v0 = s.x + add, v1 = s.y + add, v2 = s.z + add, v3 = s.w + add;
    offsets[i0 + 1] = v0; offsets[i0 + 2] = v1; offsets[i0 + 3] = v2; offsets[i0 + 4] = v3;
    uint4 cur; cur.x = v0 - c.x; cur.y = v1 - c.y; cur.z = v2 - c.z; cur.w = v3 - c.w;
    *((uint4*)(S + base) + t) = cur;
    if (base == 0 && t == 0) offsets[0] = 0u;
}

// ---------------- fill CSR entries: src | k<<18 (coef recomputed in gather) ----------------
__global__ void k_fill(const int* __restrict__ ei, const int* __restrict__ ty, int E,
                       u32* __restrict__ cursor, u32* __restrict__ entries) {
    int e = blockIdx.x * 256 + threadIdx.x;
    if (e >= E) return;
    int s = ei[e], d = ei[E + e], t = ty[e];
    if (t >= 1) {
        u32 k = (u32)(t - 1);
        u32 p = atomicAdd(&cursor[d], 1u);
        entries[p] = (u32)s | (k << 18);
    }
    if (t >= 2) {
        u32 k = (u32)(t + 2);
        u32 p = atomicAdd(&cursor[s], 1u);
        entries[p] = (u32)d | (k << 18);
    }
}

// ---------------- gather: one wave per node, lane = feature ----------------
// m_k[n,:] = d_k[n] * ( sum_src d_k[src]*h[src,:]  +  d_k[n]*h[n,:] )
__global__ __launch_bounds__(256)
void k_gather(const float* __restrict__ h, const u32* __restrict__ entries,
              const u32* __restrict__ offsets, const float* __restrict__ dinv,
              float* __restrict__ m, int N, int c0) {
    int lane = threadIdx.x & 63;
    int nl = blockIdx.x * 4 + (threadIdx.x >> 6);
    int n = c0 + nl;
    u32 beg = (u32)__builtin_amdgcn_readfirstlane((int)offsets[n]);
    u32 end = (u32)__builtin_amdgcn_readfirstlane((int)offsets[n + 1]);
    float hv = h[((size_t)n << 6) + lane];
    float d0 = dinv[n];
    float d1 = dinv[N + n];
    float d2 = dinv[2 * N + n];
    float d3 = dinv[3 * N + n];
    float d4 = dinv[4 * N + n];
    float d5 = dinv[5 * N + n];
    float d6 = dinv[6 * N + n];
    float a0 = d0 * hv, a1 = d1 * hv, a2 = d2 * hv, a3 = d3 * hv;
    float a4 = d4 * hv, a5 = d5 * hv, a6 = d6 * hv;
    for (u32 i = beg; i < end; ++i) {
        u32 pk = (u32)__builtin_amdgcn_readfirstlane((int)entries[i]);
        u32 src = pk & 0x3FFFFu;
        u32 k = pk >> 18;
        float ds = dinv[k * N + src];                 // scalar (wave-uniform) load
        float v = ds * h[((size_t)src << 6) + lane];  // coalesced 256B row
        switch (k) {
            case 0: a0 += v; break;
            case 1: a1 += v; break;
            case 2: a2 += v; break;
            case 3: a3 += v; break;
            case 4: a4 += v; break;
            case 5: a5 += v; break;
            default: a6 += v; break;
        }
    }
    float* mp = m + (size_t)nl * 448 + lane;
    mp[0]   = d0 * a0; mp[64]  = d1 * a1; mp[128] = d2 * a2; mp[192] = d3 * a3;
    mp[256] = d4 * a4; mp[320] = d5 * a5; mp[384] = d6 * a6;
}

// ---------------- stacked GEMM [64,448]x[448,64] per block + bias + relu ----------------
__global__ __launch_bounds__(256)
void k_gemm(const float* __restrict__ m, Ptr7 W, const float* __restrict__ bsum,
            float* __restrict__ hout, int c0) {
    __shared__ float a[64 * 65];
    int tid = threadIdx.x;
    int nbl = blockIdx.x << 6;                     // chunk-local node base
    int r0 = (tid >> 4) << 2, q0 = (tid & 15) << 2;
    float acc[4][4] = {};
    for (int k = 0; k < 7; k++) {
        __syncthreads();
        const float* msrc = m + (size_t)nbl * 448 + k * 64;
#pragma unroll
        for (int rep = 0; rep < 16; rep++) {
            int idx = (rep << 8) + tid;
            int nn = idx >> 6, j = idx & 63;
            a[nn * 65 + j] = msrc[(size_t)nn * 448 + j];
        }
        __syncthreads();
        const float* Wk = W.p[k];
#pragma unroll 4
        for (int j = 0; j < 64; j++) {
            float4 w4 = *(const float4*)(Wk + (j << 6) + q0);
            float av0 = a[(r0 + 0) * 65 + j];
            float av1 = a[(r0 + 1) * 65 + j];
            float av2 = a[(r0 + 2) * 65 + j];
            float av3 = a[(r0 + 3) * 65 + j];
            acc[0][0] += av0 * w4.x; acc[0][1] += av0 * w4.y; acc[0][2] += av0 * w4.z; acc[0][3] += av0 * w4.w;
            acc[1][0] += av1 * w4.x; acc[1][1] += av1 * w4.y; acc[1][2] += av1 * w4.z; acc[1][3] += av1 * w4.w;
            acc[2][0] += av2 * w4.x; acc[2][1] += av2 * w4.y; acc[2][2] += av2 * w4.z; acc[2][3] += av2 * w4.w;
            acc[3][0] += av3 * w4.x; acc[3][1] += av3 * w4.y; acc[3][2] += av3 * w4.z; acc[3][3] += av3 * w4.w;
        }
    }
    float4 b4 = *(const float4*)(bsum + q0);
#pragma unroll
    for (int rr = 0; rr < 4; rr++) {
        float4 o;
        o.x = fmaxf(acc[rr][0] + b4.x, 0.f);
        o.y = fmaxf(acc[rr][1] + b4.y, 0.f);
        o.z = fmaxf(acc[rr][2] + b4.z, 0.f);
        o.w = fmaxf(acc[rr][3] + b4.w, 0.f);
        *(float4*)(hout + (size_t)(c0 + nbl + r0 + rr) * 64 + q0) = o;
    }
}

// ---------------- pooling + 2-layer MLP head: one block per graph ----------------
__global__ __launch_bounds__(256)
void k_head(const float* __restrict__ h, const float* __restrict__ w1,
            const float* __restrict__ b1, const float* __restrict__ w2,
            const float* __restrict__ b2, float* __restrict__ out) {
    __shared__ float gmax[4][64];
    __shared__ float gl[64];
    __shared__ float t1p[4][64];
    int b = blockIdx.x;
    int tid = threadIdx.x;
    int d = tid & 63, rg = tid >> 6;
    const float* hb = h + (size_t)b * 64 * 64;
    float pm = -1e30f;
#pragma unroll
    for (int i = 0; i < 16; i++) pm = fmaxf(pm, hb[(rg * 16 + i) * 64 + d]);
    gmax[rg][d] = pm; __syncthreads();
    if (rg == 0) gl[d] = fmaxf(fmaxf(gmax[0][d], gmax[1][d]), fmaxf(gmax[2][d], gmax[3][d]));
    __syncthreads();
    float s = 0.f;
#pragma unroll
    for (int i = 0; i < 16; i++) { int dd = rg * 16 + i; s += gl[dd] * w1[dd * 64 + d]; }
    t1p[rg][d] = s; __syncthreads();
    if (rg == 0) {
        float t1 = fmaxf(t1p[0][d] + t1p[1][d] + t1p[2][d] + t1p[3][d] + b1[d], 0.f);
        float v = t1 * w2[d];
        for (int off = 32; off; off >>= 1) v += __shfl_down(v, off, 64);
        if (d == 0) out[b] = v + b2[0];
    }
}

extern "C" void kernel_launch(void* const* d_in, const int* in_sizes, int n_in,
                              void* d_out, int out_size, void* d_ws, size_t ws_size,
                              hipStream_t stream) {
    const float* x     = (const float*)d_in[0];
    const int*   ei    = (const int*)d_in[1];
    const int*   ty    = (const int*)d_in[2];
    const float* nodeW = (const float*)d_in[3];
    const float* nodeb = (const float*)d_in[4];
    const float* out1W = (const float*)d_in[5];
    const float* out1b = (const float*)d_in[6];
    const float* out2W = (const float*)d_in[7];
    const float* out2b = (const float*)d_in[8];

    Ptr7 W, B;
    W.p[0] = (const float*)d_in[9];  B.p[0] = (const float*)d_in[10];   // W1
    W.p[1] = (const float*)d_in[11]; B.p[1] = (const float*)d_in[12];   // W2
    W.p[2] = (const float*)d_in[13]; B.p[2] = (const float*)d_in[14];   // W3
    W.p[3] = (const float*)d_in[15]; B.p[3] = (const float*)d_in[16];   // W4
    W.p[4] = (const float*)d_in[17]; B.p[4] = (const float*)d_in[18];   // W2b
    W.p[5] = (const float*)d_in[19]; B.p[5] = (const float*)d_in[20];   // W3b
    W.p[6] = (const float*)d_in[21]; B.p[6] = (const float*)d_in[22];   // W4b

    const int N = in_sizes[0];       // 262144
    const int E = in_sizes[2];       // 4194304

    // ---- workspace carve (fixed part ~186 MB; m chunk sized from what's left) ----
    char* p = (char*)d_ws;
    auto carve = [&](size_t bytes) { void* r = (void*)p; p += (bytes + 255) & ~(size_t)255; return r; };
    float* hA      = (float*)carve((size_t)N * 64 * 4);
    float* hB      = (float*)carve((size_t)N * 64 * 4);
    u32*   entries = (u32*)carve((size_t)2 * E * 4);
    float* dinv    = (float*)carve((size_t)7 * N * 4);
    u32*   degcnt  = (u32*)carve((size_t)7 * N * 4);
    u32*   cnt     = (u32*)carve((size_t)N * 4);
    u32*   cursor  = (u32*)carve((size_t)N * 4);
    u32*   offsets = (u32*)carve((size_t)(N + 1) * 4);
    u32*   bsums   = (u32*)carve(1024);
    u32*   bexcl   = (u32*)carve(1024);
    float* bsum    = (float*)carve(256);
    size_t used = (size_t)(p - (char*)d_ws);
    size_t avail = (ws_size > used) ? (ws_size - used) : 0;
    size_t chunkNodes = (avail / (448 * 4)) & ~(size_t)63;   // multiple of 64
    if (chunkNodes < 64) chunkNodes = 64;
    if (chunkNodes > (size_t)N) chunkNodes = (size_t)N;
    float* m = (float*)p;
    (void)n_in; (void)out_size;

    hipMemsetAsync(degcnt, 0, (size_t)7 * N * 4, stream);
    hipMemsetAsync(cnt, 0, (size_t)N * 4, stream);

    k_init_h<<<(N * 64) / 256, 256, 0, stream>>>(x, nodeW, nodeb, hA, N * 64);
    k_edge_count<<<(E + 255) / 256, 256, 0, stream>>>(ei, ty, E, N, degcnt, cnt);
    k_dinv<<<(7 * N + 255) / 256, 256, 0, stream>>>(degcnt, dinv, 7 * N);
    k_bsum<<<1, 64, 0, stream>>>(B, bsum);

    int nScanBlocks = N / 1024;  // 256
    k_scan1<<<nScanBlocks, 256, 0, stream>>>(cnt, cursor, bsums);
    k_scan2<<<1, 256, 0, stream>>>(bsums, bexcl, nScanBlocks);
    k_scan3<<<nScanBlocks, 256, 0, stream>>>(cursor, cnt, bexcl, offsets);
    k_fill<<<(E + 255) / 256, 256, 0, stream>>>(ei, ty, E, cursor, entries);

    float* hcur = hA;
    float* hnext = hB;
    for (int depth = 0; depth < 3; depth++) {
        for (int c0 = 0; c0 < N; c0 += (int)chunkNodes) {
            int cn = (int)(((size_t)(N - c0) < chunkNodes) ? (size_t)(N - c0) : chunkNodes);
            k_gather<<<cn / 4, 256, 0, stream>>>(hcur, entries, offsets, dinv, m, N, c0);
            k_gemm<<<cn / 64, 256, 0, stream>>>(m, W, bsum, hnext, c0);
        }
        float* t = hcur; hcur = hnext; hnext = t;
    }

    k_head<<<N / 64, 256, 0, stream>>>(hcur, out1W, out1b, out2W, out2b, (float*)d_out);
}

// Round 3
// 2677.200 us; speedup vs baseline: 1.2652x; 1.2652x over previous
//
#include <hip/hip_runtime.h>
#include <stdint.h>

typedef unsigned int u32;

struct Ptr7 { const float* p[7]; };

__device__ __forceinline__ int rfl(int v) { return __builtin_amdgcn_readfirstlane(v); }
__device__ __forceinline__ float rlane_f(float v, int j) {
    return __int_as_float(__builtin_amdgcn_readlane(__float_as_int(v), j));
}

// ---------------- degree counts (per-type, aggregation-target) ----------------
__global__ void k_edge_count(const int* __restrict__ ei, const int* __restrict__ ty,
                             int E, int N, u32* __restrict__ degcnt) {
    int e = blockIdx.x * 256 + threadIdx.x;
    if (e >= E) return;
    int s = ei[e], d = ei[E + e], t = ty[e];
    if (t >= 1) atomicAdd(&degcnt[(t - 1) * N + d], 1u);
    if (t >= 2) atomicAdd(&degcnt[(t + 2) * N + s], 1u);
}

// ---------------- dinv + total contribution count ----------------
__global__ void k_dinv_cnt(const u32* __restrict__ degcnt, float* __restrict__ dinv,
                           u32* __restrict__ cnt, int N) {
    int n = blockIdx.x * 256 + threadIdx.x;
    if (n >= N) return;
    u32 c = 0;
#pragma unroll
    for (int k = 0; k < 7; k++) {
        u32 g = degcnt[k * N + n];
        c += g;
        dinv[k * N + n] = rsqrtf(1.0f + (float)g);
    }
    cnt[n] = c;
}

__global__ void k_bsum(Ptr7 b, float* __restrict__ bsum) {
    int d = threadIdx.x;
    float s = 0.f;
#pragma unroll
    for (int k = 0; k < 7; k++) s += b.p[k][d];
    bsum[d] = s;
}

// ---------------- U_k = nW @ W_k, V_k = nb @ W_k  (7 blocks x 64) ----------------
__global__ void k_uv(const float* __restrict__ nW, const float* __restrict__ nb,
                     Ptr7 W, float* __restrict__ U, float* __restrict__ V) {
    int k = blockIdx.x, d = threadIdx.x;
    const float* Wk = W.p[k];
    float u = 0.f, v = 0.f;
#pragma unroll 8
    for (int j = 0; j < 64; j++) {
        float w = Wk[j * 64 + d];
        u += nW[j] * w;
        v += nb[j] * w;
    }
    U[k * 64 + d] = u;
    V[k * 64 + d] = v;
}

// ---------------- 3-pass exclusive scan (chunk = 1024/block) ----------------
__global__ void k_scan1(const u32* __restrict__ cnt, u32* __restrict__ S, u32* __restrict__ bsums) {
    __shared__ u32 lds[256];
    int t = threadIdx.x;
    int base = blockIdx.x * 1024;
    uint4 c = *((const uint4*)(cnt + base) + t);
    u32 s0 = c.x, s1 = s0 + c.y, s2 = s1 + c.z, s3 = s2 + c.w;
    lds[t] = s3; __syncthreads();
    for (int off = 1; off < 256; off <<= 1) {
        u32 v = (t >= off) ? lds[t - off] : 0u;
        __syncthreads();
        lds[t] += v;
        __syncthreads();
    }
    u32 excl = lds[t] - s3;
    uint4 o; o.x = excl + s0; o.y = excl + s1; o.z = excl + s2; o.w = excl + s3;
    *((uint4*)(S + base) + t) = o;
    if (t == 255) bsums[blockIdx.x] = lds[255];
}

__global__ void k_scan2(const u32* __restrict__ bsums, u32* __restrict__ bexcl, int nb) {
    __shared__ u32 lds[256];
    int t = threadIdx.x;
    u32 v = (t < nb) ? bsums[t] : 0u;
    lds[t] = v; __syncthreads();
    for (int off = 1; off < 256; off <<= 1) {
        u32 x2 = (t >= off) ? lds[t - off] : 0u;
        __syncthreads();
        lds[t] += x2;
        __syncthreads();
    }
    if (t < nb) bexcl[t] = lds[t] - v;
}

__global__ void k_scan3(u32* __restrict__ S, const u32* __restrict__ cnt,
                        const u32* __restrict__ bexcl, u32* __restrict__ offsets) {
    int t = threadIdx.x;
    int base = blockIdx.x * 1024;
    u32 add = bexcl[blockIdx.x];
    uint4 s = *((const uint4*)(S + base) + t);
    uint4 c = *((const uint4*)(cnt + base) + t);
    int i0 = base + t * 4;
    u32 v0 = s.x + add, v1 = s.y + add, v2 = s.z + add, v3 = s.w + add;
    offsets[i0 + 1] = v0; offsets[i0 + 2] = v1; offsets[i0 + 3] = v2; offsets[i0 + 4] = v3;
    uint4 cur; cur.x = v0 - c.x; cur.y = v1 - c.y; cur.z = v2 - c.z; cur.w = v3 - c.w;
    *((uint4*)(S + base) + t) = cur;
    if (base == 0 && t == 0) offsets[0] = 0u;
}

// ---------------- fill CSR entries: src | k<<18 ----------------
__global__ void k_fill(const int* __restrict__ ei, const int* __restrict__ ty, int E,
                       u32* __restrict__ cursor, u32* __restrict__ entries) {
    int e = blockIdx.x * 256 + threadIdx.x;
    if (e >= E) return;
    int s = ei[e], d = ei[E + e], t = ty[e];
    if (t >= 1) {
        u32 k = (u32)(t - 1);
        u32 p = atomicAdd(&cursor[d], 1u);
        __builtin_nontemporal_store((u32)s | (k << 18), &entries[p]);
    }
    if (t >= 2) {
        u32 k = (u32)(t + 2);
        u32 p = atomicAdd(&cursor[s], 1u);
        __builtin_nontemporal_store((u32)d | (k << 18), &entries[p]);
    }
}

// ---------------- depth-1 light gather: P/Q per (node, k) ----------------
__global__ __launch_bounds__(256)
void k_gather1(const float* __restrict__ x, const u32* __restrict__ entries,
               const u32* __restrict__ offsets, const float* __restrict__ dinv,
               int N, float* __restrict__ P, float* __restrict__ Q) {
    int lane = threadIdx.x & 63;
    int n = blockIdx.x * 4 + (threadIdx.x >> 6);
    u32 beg = (u32)rfl((int)offsets[n]);
    u32 end = (u32)rfl((int)offsets[n + 1]);
    float sa0 = 0, sa1 = 0, sa2 = 0, sa3 = 0, sa4 = 0, sa5 = 0, sa6 = 0;
    float sc0 = 0, sc1 = 0, sc2 = 0, sc3 = 0, sc4 = 0, sc5 = 0, sc6 = 0;
    for (u32 base = beg; base < end; base += 64) {
        u32 rem = end - base;
        if ((u32)lane < rem) {
            u32 e = entries[base + lane];
            u32 src = e & 0x3FFFFu;
            u32 k = e >> 18;
            float ds = dinv[k * N + src];
            float val = ds * x[src];
            sa0 += (k == 0) ? val : 0.f; sc0 += (k == 0) ? ds : 0.f;
            sa1 += (k == 1) ? val : 0.f; sc1 += (k == 1) ? ds : 0.f;
            sa2 += (k == 2) ? val : 0.f; sc2 += (k == 2) ? ds : 0.f;
            sa3 += (k == 3) ? val : 0.f; sc3 += (k == 3) ? ds : 0.f;
            sa4 += (k == 4) ? val : 0.f; sc4 += (k == 4) ? ds : 0.f;
            sa5 += (k == 5) ? val : 0.f; sc5 += (k == 5) ? ds : 0.f;
            sa6 += (k == 6) ? val : 0.f; sc6 += (k == 6) ? ds : 0.f;
        }
    }
#pragma unroll
    for (int off = 1; off < 64; off <<= 1) {
        sa0 += __shfl_xor(sa0, off, 64); sc0 += __shfl_xor(sc0, off, 64);
        sa1 += __shfl_xor(sa1, off, 64); sc1 += __shfl_xor(sc1, off, 64);
        sa2 += __shfl_xor(sa2, off, 64); sc2 += __shfl_xor(sc2, off, 64);
        sa3 += __shfl_xor(sa3, off, 64); sc3 += __shfl_xor(sc3, off, 64);
        sa4 += __shfl_xor(sa4, off, 64); sc4 += __shfl_xor(sc4, off, 64);
        sa5 += __shfl_xor(sa5, off, 64); sc5 += __shfl_xor(sc5, off, 64);
        sa6 += __shfl_xor(sa6, off, 64); sc6 += __shfl_xor(sc6, off, 64);
    }
    if (lane < 7) {
        float sa = (lane == 0) ? sa0 : (lane == 1) ? sa1 : (lane == 2) ? sa2 :
                   (lane == 3) ? sa3 : (lane == 4) ? sa4 : (lane == 5) ? sa5 : sa6;
        float sc = (lane == 0) ? sc0 : (lane == 1) ? sc1 : (lane == 2) ? sc2 :
                   (lane == 3) ? sc3 : (lane == 4) ? sc4 : (lane == 5) ? sc5 : sc6;
        float dn = dinv[lane * N + n];
        float xn = x[n];
        P[n * 8 + lane] = dn * (sa + dn * xn);
        Q[n * 8 + lane] = dn * (sc + dn);
    }
}

// ---------------- h1 = relu(P@U + Q@V + bsum) ----------------
__global__ __launch_bounds__(256)
void k_h1(const float* __restrict__ P, const float* __restrict__ Q,
          const float* __restrict__ U, const float* __restrict__ V,
          const float* __restrict__ bsum, float* __restrict__ h1) {
    int i = blockIdx.x * 256 + threadIdx.x;
    int n = rfl(i >> 6);
    int d = i & 63;
    float acc = bsum[d];
#pragma unroll
    for (int k = 0; k < 7; k++)
        acc += P[n * 8 + k] * U[k * 64 + d] + Q[n * 8 + k] * V[k * 64 + d];
    h1[((size_t)n << 6) + d] = fmaxf(acc, 0.f);
}

// ---------------- full gather (depths 2,3): wave per node, batched entries ----------------
__global__ __launch_bounds__(256)
void k_gather(const float* __restrict__ h, const u32* __restrict__ entries,
              const u32* __restrict__ offsets, const float* __restrict__ dinv,
              float* __restrict__ m, int N, int c0) {
    int lane = threadIdx.x & 63;
    int nl = blockIdx.x * 4 + (threadIdx.x >> 6);
    int n = c0 + nl;
    u32 beg = (u32)rfl((int)offsets[n]);
    u32 end = (u32)rfl((int)offsets[n + 1]);
    float hv = h[((size_t)n << 6) + lane];
    float d0 = dinv[n],         d1 = dinv[N + n],     d2 = dinv[2 * N + n];
    float d3 = dinv[3 * N + n], d4 = dinv[4 * N + n], d5 = dinv[5 * N + n];
    float d6 = dinv[6 * N + n];
    float a0 = d0 * hv, a1 = d1 * hv, a2 = d2 * hv, a3 = d3 * hv;
    float a4 = d4 * hv, a5 = d5 * hv, a6 = d6 * hv;
    for (u32 base = beg; base < end; base += 64) {
        u32 rem = end - base;
        u32 e = 0; float dsv = 0.f;
        if ((u32)lane < rem) {
            e = entries[base + lane];
            dsv = dinv[(e >> 18) * N + (e & 0x3FFFFu)];
        }
        int cnt = (rem < 64u) ? (int)rem : 64;
        for (int j = 0; j < cnt; ++j) {
            u32 pk = (u32)__builtin_amdgcn_readlane((int)e, j);
            float cf = rlane_f(dsv, j);
            u32 src = pk & 0x3FFFFu;
            u32 k = pk >> 18;
            float hval = h[((size_t)src << 6) + lane];
            float c0s = (k == 0) ? cf : 0.f;
            float c1s = (k == 1) ? cf : 0.f;
            float c2s = (k == 2) ? cf : 0.f;
            float c3s = (k == 3) ? cf : 0.f;
            float c4s = (k == 4) ? cf : 0.f;
            float c5s = (k == 5) ? cf : 0.f;
            float c6s = (k == 6) ? cf : 0.f;
            a0 = fmaf(c0s, hval, a0);
            a1 = fmaf(c1s, hval, a1);
            a2 = fmaf(c2s, hval, a2);
            a3 = fmaf(c3s, hval, a3);
            a4 = fmaf(c4s, hval, a4);
            a5 = fmaf(c5s, hval, a5);
            a6 = fmaf(c6s, hval, a6);
        }
    }
    float* mp = m + (size_t)nl * 448 + lane;
    mp[0]   = d0 * a0; mp[64]  = d1 * a1; mp[128] = d2 * a2; mp[192] = d3 * a3;
    mp[256] = d4 * a4; mp[320] = d5 * a5; mp[384] = d6 * a6;
}

// ---------------- stacked GEMM [64,448]x[448,64] per block + bias + relu ----------------
__global__ __launch_bounds__(256)
void k_gemm(const float* __restrict__ m, Ptr7 W, const float* __restrict__ bsum,
            float* __restrict__ hout, int c0) {
    __shared__ float a[64 * 65];
    int tid = threadIdx.x;
    int nbl = blockIdx.x << 6;
    int r0 = (tid >> 4) << 2, q0 = (tid & 15) << 2;
    float acc[4][4] = {};
    for (int k = 0; k < 7; k++) {
        __syncthreads();
        const float* msrc = m + (size_t)nbl * 448 + k * 64;
#pragma unroll
        for (int rep = 0; rep < 16; rep++) {
            int idx = (rep << 8) + tid;
            int nn = idx >> 6, j = idx & 63;
            a[nn * 65 + j] = msrc[(size_t)nn * 448 + j];
        }
        __syncthreads();
        const float* Wk = W.p[k];
#pragma unroll 4
        for (int j = 0; j < 64; j++) {
            float4 w4 = *(const float4*)(Wk + (j << 6) + q0);
            float av0 = a[(r0 + 0) * 65 + j];
            float av1 = a[(r0 + 1) * 65 + j];
            float av2 = a[(r0 + 2) * 65 + j];
            float av3 = a[(r0 + 3) * 65 + j];
            acc[0][0] += av0 * w4.x; acc[0][1] += av0 * w4.y; acc[0][2] += av0 * w4.z; acc[0][3] += av0 * w4.w;
            acc[1][0] += av1 * w4.x; acc[1][1] += av1 * w4.y; acc[1][2] += av1 * w4.z; acc[1][3] += av1 * w4.w;
            acc[2][0] += av2 * w4.x; acc[2][1] += av2 * w4.y; acc[2][2] += av2 * w4.z; acc[2][3] += av2 * w4.w;
            acc[3][0] += av3 * w4.x; acc[3][1] += av3 * w4.y; acc[3][2] += av3 * w4.z; acc[3][3] += av3 * w4.w;
        }
    }
    float4 b4 = *(const float4*)(bsum + q0);
#pragma unroll
    for (int rr = 0; rr < 4; rr++) {
        float4 o;
        o.x = fmaxf(acc[rr][0] + b4.x, 0.f);
        o.y = fmaxf(acc[rr][1] + b4.y, 0.f);
        o.z = fmaxf(acc[rr][2] + b4.z, 0.f);
        o.w = fmaxf(acc[rr][3] + b4.w, 0.f);
        *(float4*)(hout + (size_t)(c0 + nbl + r0 + rr) * 64 + q0) = o;
    }
}

// ---------------- pooling + 2-layer MLP head ----------------
__global__ __launch_bounds__(256)
void k_head(const float* __restrict__ h, const float* __restrict__ w1,
            const float* __restrict__ b1, const float* __restrict__ w2,
            const float* __restrict__ b2, float* __restrict__ out) {
    __shared__ float gmax[4][64];
    __shared__ float gl[64];
    __shared__ float t1p[4][64];
    int b = blockIdx.x;
    int tid = threadIdx.x;
    int d = tid & 63, rg = tid >> 6;
    const float* hb = h + (size_t)b * 64 * 64;
    float pm = -1e30f;
#pragma unroll
    for (int i = 0; i < 16; i++) pm = fmaxf(pm, hb[(rg * 16 + i) * 64 + d]);
    gmax[rg][d] = pm; __syncthreads();
    if (rg == 0) gl[d] = fmaxf(fmaxf(gmax[0][d], gmax[1][d]), fmaxf(gmax[2][d], gmax[3][d]));
    __syncthreads();
    float s = 0.f;
#pragma unroll
    for (int i = 0; i < 16; i++) { int dd = rg * 16 + i; s += gl[dd] * w1[dd * 64 + d]; }
    t1p[rg][d] = s; __syncthreads();
    if (rg == 0) {
        float t1 = fmaxf(t1p[0][d] + t1p[1][d] + t1p[2][d] + t1p[3][d] + b1[d], 0.f);
        float v = t1 * w2[d];
        for (int off = 32; off; off >>= 1) v += __shfl_down(v, off, 64);
        if (d == 0) out[b] = v + b2[0];
    }
}

extern "C" void kernel_launch(void* const* d_in, const int* in_sizes, int n_in,
                              void* d_out, int out_size, void* d_ws, size_t ws_size,
                              hipStream_t stream) {
    const float* x     = (const float*)d_in[0];
    const int*   ei    = (const int*)d_in[1];
    const int*   ty    = (const int*)d_in[2];
    const float* nodeW = (const float*)d_in[3];
    const float* nodeb = (const float*)d_in[4];
    const float* out1W = (const float*)d_in[5];
    const float* out1b = (const float*)d_in[6];
    const float* out2W = (const float*)d_in[7];
    const float* out2b = (const float*)d_in[8];

    Ptr7 W, B;
    W.p[0] = (const float*)d_in[9];  B.p[0] = (const float*)d_in[10];   // W1
    W.p[1] = (const float*)d_in[11]; B.p[1] = (const float*)d_in[12];   // W2
    W.p[2] = (const float*)d_in[13]; B.p[2] = (const float*)d_in[14];   // W3
    W.p[3] = (const float*)d_in[15]; B.p[3] = (const float*)d_in[16];   // W4
    W.p[4] = (const float*)d_in[17]; B.p[4] = (const float*)d_in[18];   // W2b
    W.p[5] = (const float*)d_in[19]; B.p[5] = (const float*)d_in[20];   // W3b
    W.p[6] = (const float*)d_in[21]; B.p[6] = (const float*)d_in[22];   // W4b

    const int N = in_sizes[0];       // 262144
    const int E = in_sizes[2];       // 4194304

    char* p = (char*)d_ws;
    auto carve = [&](size_t bytes) { void* r = (void*)p; p += (bytes + 255) & ~(size_t)255; return r; };
    float* hA      = (float*)carve((size_t)N * 64 * 4);
    float* hB      = (float*)carve((size_t)N * 64 * 4);
    u32*   entries = (u32*)carve((size_t)2 * E * 4);
    float* dinv    = (float*)carve((size_t)7 * N * 4);
    u32*   degcnt  = (u32*)carve((size_t)7 * N * 4);
    u32*   cnt     = (u32*)carve((size_t)N * 4);
    u32*   cursor  = (u32*)carve((size_t)N * 4);
    u32*   offsets = (u32*)carve((size_t)(N + 1) * 4);
    float* P       = (float*)carve((size_t)N * 8 * 4);
    float* Q       = (float*)carve((size_t)N * 8 * 4);
    float* U       = (float*)carve(7 * 64 * 4);
    float* V       = (float*)carve(7 * 64 * 4);
    u32*   bsums   = (u32*)carve(1024);
    u32*   bexcl   = (u32*)carve(1024);
    float* bsum    = (float*)carve(256);
    size_t used = (size_t)(p - (char*)d_ws);
    size_t avail = (ws_size > used) ? (ws_size - used) : 0;
    size_t chunkNodes = (avail / (448 * 4)) & ~(size_t)63;
    if (chunkNodes < 64) chunkNodes = 64;
    if (chunkNodes > 32768) chunkNodes = 32768;             // keep m L3-resident
    if (chunkNodes > (size_t)N) chunkNodes = (size_t)N;
    float* m = (float*)p;
    (void)n_in; (void)out_size;

    hipMemsetAsync(degcnt, 0, (size_t)7 * N * 4, stream);

    k_edge_count<<<(E + 255) / 256, 256, 0, stream>>>(ei, ty, E, N, degcnt);
    k_dinv_cnt<<<(N + 255) / 256, 256, 0, stream>>>(degcnt, dinv, cnt, N);
    k_bsum<<<1, 64, 0, stream>>>(B, bsum);
    k_uv<<<7, 64, 0, stream>>>(nodeW, nodeb, W, U, V);

    int nScanBlocks = N / 1024;  // 256
    k_scan1<<<nScanBlocks, 256, 0, stream>>>(cnt, cursor, bsums);
    k_scan2<<<1, 256, 0, stream>>>(bsums, bexcl, nScanBlocks);
    k_scan3<<<nScanBlocks, 256, 0, stream>>>(cursor, cnt, bexcl, offsets);
    k_fill<<<(E + 255) / 256, 256, 0, stream>>>(ei, ty, E, cursor, entries);

    // depth 1 via rank-2 shortcut
    k_gather1<<<N / 4, 256, 0, stream>>>(x, entries, offsets, dinv, N, P, Q);
    k_h1<<<(N * 64) / 256, 256, 0, stream>>>(P, Q, U, V, bsum, hA);

    // depths 2,3: full gather + GEMM, chunked
    float* hcur = hA;
    float* hnext = hB;
    for (int depth = 0; depth < 2; depth++) {
        for (int c0 = 0; c0 < N; c0 += (int)chunkNodes) {
            int cn = (int)(((size_t)(N - c0) < chunkNodes) ? (size_t)(N - c0) : chunkNodes);
            k_gather<<<cn / 4, 256, 0, stream>>>(hcur, entries, offsets, dinv, m, N, c0);
            k_gemm<<<cn / 64, 256, 0, stream>>>(m, W, bsum, hnext, c0);
        }
        float* t = hcur; hcur = hnext; hnext = t;
    }

    k_head<<<N / 64, 256, 0, stream>>>(hcur, out1W, out1b, out2W, out2b, (float*)d_out);
}

// Round 4
// 2151.087 us; speedup vs baseline: 1.5746x; 1.2446x over previous
//
#include <hip/hip_runtime.h>
#include <stdint.h>

typedef unsigned int u32;

struct Ptr7 { const float* p[7]; };

__device__ __forceinline__ int rfl(int v) { return __builtin_amdgcn_readfirstlane(v); }
__device__ __forceinline__ float rlane_f(float v, int j) {
    return __int_as_float(__builtin_amdgcn_readlane(__float_as_int(v), j));
}

// ================= bucketed CSR build =================
// item = src(18b) | k(3b)<<18 | dstlocal(10b)<<21 ; bucket = target >> 10

// ---- hist: per-bucket item counts ----
__global__ __launch_bounds__(256)
void k_hist(const int* __restrict__ ei, const int* __restrict__ ty, int E,
            u32* __restrict__ bucketCnt) {
    __shared__ u32 hist[256];
    int tid = threadIdx.x;
    hist[tid] = 0;
    __syncthreads();
    for (int e = blockIdx.x * 256 + tid; e < E; e += gridDim.x * 256) {
        int s = ei[e], d = ei[E + e], t = ty[e];
        if (t >= 1) atomicAdd(&hist[(u32)d >> 10], 1u);
        if (t >= 2) atomicAdd(&hist[(u32)s >> 10], 1u);
    }
    __syncthreads();
    if (hist[tid]) atomicAdd(&bucketCnt[tid], hist[tid]);
}

// ---- scan bucket counts -> bucketBase, init gcursor ----
__global__ void k_bucket_scan(const u32* __restrict__ bucketCnt,
                              u32* __restrict__ bucketBase, u32* __restrict__ gcursor) {
    __shared__ u32 wsum[4];
    int tid = threadIdx.x;
    u32 v = bucketCnt[tid];
    u32 sc = v;
    for (int off = 1; off < 64; off <<= 1) {
        u32 t2 = __shfl_up(sc, off, 64);
        if ((tid & 63) >= off) sc += t2;
    }
    if ((tid & 63) == 63) wsum[tid >> 6] = sc;
    __syncthreads();
    u32 wadd = 0;
    int w = tid >> 6;
    if (w > 0) wadd += wsum[0];
    if (w > 1) wadd += wsum[1];
    if (w > 2) wadd += wsum[2];
    u32 incl = sc + wadd;
    u32 excl = incl - v;
    bucketBase[tid] = excl;
    gcursor[tid] = excl;
    if (tid == 255) bucketBase[256] = incl;
}

// ---- passA: bin items into bucket segments (block-contiguous) ----
__global__ __launch_bounds__(256)
void k_passA(const int* __restrict__ ei, const int* __restrict__ ty, int E,
             u32* __restrict__ gcursor, u32* __restrict__ tmpItems) {
    __shared__ u32 hist[256], gb[256], cur[256];
    int tid = threadIdx.x;
    int e0 = blockIdx.x * 4096;
    hist[tid] = 0;
    __syncthreads();
#pragma unroll
    for (int i = 0; i < 16; i++) {
        int e = e0 + i * 256 + tid;
        if (e < E) {
            int s = ei[e], d = ei[E + e], t = ty[e];
            if (t >= 1) atomicAdd(&hist[(u32)d >> 10], 1u);
            if (t >= 2) atomicAdd(&hist[(u32)s >> 10], 1u);
        }
    }
    __syncthreads();
    u32 h = hist[tid];
    gb[tid] = h ? atomicAdd(&gcursor[tid], h) : 0u;
    cur[tid] = 0;
    __syncthreads();
#pragma unroll
    for (int i = 0; i < 16; i++) {
        int e = e0 + i * 256 + tid;
        if (e < E) {
            int s = ei[e], d = ei[E + e], t = ty[e];
            if (t >= 1) {
                u32 b = (u32)d >> 10;
                u32 slot = atomicAdd(&cur[b], 1u);
                tmpItems[gb[b] + slot] = (u32)s | ((u32)(t - 1) << 18) | (((u32)d & 1023u) << 21);
            }
            if (t >= 2) {
                u32 b = (u32)s >> 10;
                u32 slot = atomicAdd(&cur[b], 1u);
                tmpItems[gb[b] + slot] = (u32)d | ((u32)(t + 2) << 18) | (((u32)s & 1023u) << 21);
            }
        }
    }
}

// ---- passB: per-bucket (node,k) degree count -> dinv, cnt (all coalesced) ----
__global__ __launch_bounds__(256)
void k_passB(const u32* __restrict__ tmpItems, const u32* __restrict__ bucketBase,
             float* __restrict__ dinv, u32* __restrict__ cnt, int N) {
    __shared__ u32 c[1024 * 8];
    int b = blockIdx.x, tid = threadIdx.x;
    for (int i = tid; i < 8192; i += 256) c[i] = 0;
    __syncthreads();
    u32 beg = bucketBase[b], end = bucketBase[b + 1];
    for (u32 i = beg + tid; i < end; i += 256) {
        u32 it = tmpItems[i];
        atomicAdd(&c[(it >> 21) * 8 + ((it >> 18) & 7)], 1u);
    }
    __syncthreads();
    int nodeBase = b << 10;
    for (int l = tid; l < 1024; l += 256) {
        int n = nodeBase + l;
        u32 tot = 0;
#pragma unroll
        for (int k = 0; k < 7; k++) {
            u32 g = c[l * 8 + k];
            tot += g;
            dinv[k * N + n] = rsqrtf(1.0f + (float)g);
        }
        cnt[n] = tot;
    }
}

// ---- passC: per-bucket scatter into final CSR (L2-local region) ----
__global__ __launch_bounds__(256)
void k_passC(const u32* __restrict__ tmpItems, const u32* __restrict__ bucketBase,
             const u32* __restrict__ offsets, u32* __restrict__ entries) {
    __shared__ u32 cur[1024];
    int b = blockIdx.x, tid = threadIdx.x;
    int nodeBase = b << 10;
    for (int l = tid; l < 1024; l += 256) cur[l] = offsets[nodeBase + l];
    __syncthreads();
    u32 beg = bucketBase[b], end = bucketBase[b + 1];
    for (u32 i = beg + tid; i < end; i += 256) {
        u32 it = tmpItems[i];
        u32 p = atomicAdd(&cur[it >> 21], 1u);
        entries[p] = it & 0x1FFFFFu;
    }
}

// ================= shared small kernels =================
__global__ void k_bsum(Ptr7 b, float* __restrict__ bsum) {
    int d = threadIdx.x;
    float s = 0.f;
#pragma unroll
    for (int k = 0; k < 7; k++) s += b.p[k][d];
    bsum[d] = s;
}

__global__ void k_uv(const float* __restrict__ nW, const float* __restrict__ nb,
                     Ptr7 W, float* __restrict__ U, float* __restrict__ V) {
    int k = blockIdx.x, d = threadIdx.x;
    const float* Wk = W.p[k];
    float u = 0.f, v = 0.f;
#pragma unroll 8
    for (int j = 0; j < 64; j++) {
        float w = Wk[j * 64 + d];
        u += nW[j] * w;
        v += nb[j] * w;
    }
    U[k * 64 + d] = u;
    V[k * 64 + d] = v;
}

// ---------------- 3-pass exclusive scan (chunk = 1024/block) ----------------
__global__ void k_scan1(const u32* __restrict__ cnt, u32* __restrict__ S, u32* __restrict__ bsums) {
    __shared__ u32 lds[256];
    int t = threadIdx.x;
    int base = blockIdx.x * 1024;
    uint4 c = *((const uint4*)(cnt + base) + t);
    u32 s0 = c.x, s1 = s0 + c.y, s2 = s1 + c.z, s3 = s2 + c.w;
    lds[t] = s3; __syncthreads();
    for (int off = 1; off < 256; off <<= 1) {
        u32 v = (t >= off) ? lds[t - off] : 0u;
        __syncthreads();
        lds[t] += v;
        __syncthreads();
    }
    u32 excl = lds[t] - s3;
    uint4 o; o.x = excl + s0; o.y = excl + s1; o.z = excl + s2; o.w = excl + s3;
    *((uint4*)(S + base) + t) = o;
    if (t == 255) bsums[blockIdx.x] = lds[255];
}

__global__ void k_scan2(const u32* __restrict__ bsums, u32* __restrict__ bexcl, int nb) {
    __shared__ u32 lds[256];
    int t = threadIdx.x;
    u32 v = (t < nb) ? bsums[t] : 0u;
    lds[t] = v; __syncthreads();
    for (int off = 1; off < 256; off <<= 1) {
        u32 x2 = (t >= off) ? lds[t - off] : 0u;
        __syncthreads();
        lds[t] += x2;
        __syncthreads();
    }
    if (t < nb) bexcl[t] = lds[t] - v;
}

__global__ void k_scan3(u32* __restrict__ S, const u32* __restrict__ cnt,
                        const u32* __restrict__ bexcl, u32* __restrict__ offsets) {
    int t = threadIdx.x;
    int base = blockIdx.x * 1024;
    u32 add = bexcl[blockIdx.x];
    uint4 s = *((const uint4*)(S + base) + t);
    uint4 c = *((const uint4*)(cnt + base) + t);
    int i0 = base + t * 4;
    u32 v0 = s.x + add, v1 = s.y + add, v2 = s.z + add, v3 = s.w + add;
    offsets[i0 + 1] = v0; offsets[i0 + 2] = v1; offsets[i0 + 3] = v2; offsets[i0 + 4] = v3;
    if (base == 0 && t == 0) offsets[0] = 0u;
}

// ---------------- depth-1 light gather: P/Q per (node, k) ----------------
__global__ __launch_bounds__(256)
void k_gather1(const float* __restrict__ x, const u32* __restrict__ entries,
               const u32* __restrict__ offsets, const float* __restrict__ dinv,
               int N, float* __restrict__ P, float* __restrict__ Q) {
    int lane = threadIdx.x & 63;
    int n = blockIdx.x * 4 + (threadIdx.x >> 6);
    u32 beg = (u32)rfl((int)offsets[n]);
    u32 end = (u32)rfl((int)offsets[n + 1]);
    float sa0 = 0, sa1 = 0, sa2 = 0, sa3 = 0, sa4 = 0, sa5 = 0, sa6 = 0;
    float sc0 = 0, sc1 = 0, sc2 = 0, sc3 = 0, sc4 = 0, sc5 = 0, sc6 = 0;
    for (u32 base = beg; base < end; base += 64) {
        u32 rem = end - base;
        if ((u32)lane < rem) {
            u32 e = entries[base + lane];
            u32 src = e & 0x3FFFFu;
            u32 k = e >> 18;
            float ds = dinv[k * N + src];
            float val = ds * x[src];
            sa0 += (k == 0) ? val : 0.f; sc0 += (k == 0) ? ds : 0.f;
            sa1 += (k == 1) ? val : 0.f; sc1 += (k == 1) ? ds : 0.f;
            sa2 += (k == 2) ? val : 0.f; sc2 += (k == 2) ? ds : 0.f;
            sa3 += (k == 3) ? val : 0.f; sc3 += (k == 3) ? ds : 0.f;
            sa4 += (k == 4) ? val : 0.f; sc4 += (k == 4) ? ds : 0.f;
            sa5 += (k == 5) ? val : 0.f; sc5 += (k == 5) ? ds : 0.f;
            sa6 += (k == 6) ? val : 0.f; sc6 += (k == 6) ? ds : 0.f;
        }
    }
#pragma unroll
    for (int off = 1; off < 64; off <<= 1) {
        sa0 += __shfl_xor(sa0, off, 64); sc0 += __shfl_xor(sc0, off, 64);
        sa1 += __shfl_xor(sa1, off, 64); sc1 += __shfl_xor(sc1, off, 64);
        sa2 += __shfl_xor(sa2, off, 64); sc2 += __shfl_xor(sc2, off, 64);
        sa3 += __shfl_xor(sa3, off, 64); sc3 += __shfl_xor(sc3, off, 64);
        sa4 += __shfl_xor(sa4, off, 64); sc4 += __shfl_xor(sc4, off, 64);
        sa5 += __shfl_xor(sa5, off, 64); sc5 += __shfl_xor(sc5, off, 64);
        sa6 += __shfl_xor(sa6, off, 64); sc6 += __shfl_xor(sc6, off, 64);
    }
    if (lane < 7) {
        float sa = (lane == 0) ? sa0 : (lane == 1) ? sa1 : (lane == 2) ? sa2 :
                   (lane == 3) ? sa3 : (lane == 4) ? sa4 : (lane == 5) ? sa5 : sa6;
        float sc = (lane == 0) ? sc0 : (lane == 1) ? sc1 : (lane == 2) ? sc2 :
                   (lane == 3) ? sc3 : (lane == 4) ? sc4 : (lane == 5) ? sc5 : sc6;
        float dn = dinv[lane * N + n];
        float xn = x[n];
        P[n * 8 + lane] = dn * (sa + dn * xn);
        Q[n * 8 + lane] = dn * (sc + dn);
    }
}

// ---------------- h1 = relu(P@U + Q@V + bsum) ----------------
__global__ __launch_bounds__(256)
void k_h1(const float* __restrict__ P, const float* __restrict__ Q,
          const float* __restrict__ U, const float* __restrict__ V,
          const float* __restrict__ bsum, float* __restrict__ h1) {
    int i = blockIdx.x * 256 + threadIdx.x;
    int n = rfl(i >> 6);
    int d = i & 63;
    float acc = bsum[d];
#pragma unroll
    for (int k = 0; k < 7; k++)
        acc += P[n * 8 + k] * U[k * 64 + d] + Q[n * 8 + k] * V[k * 64 + d];
    h1[((size_t)n << 6) + d] = fmaxf(acc, 0.f);
}

// ---------------- full gather (depths 2,3): wave per node, batched entries ----------------
__global__ __launch_bounds__(256)
void k_gather(const float* __restrict__ h, const u32* __restrict__ entries,
              const u32* __restrict__ offsets, const float* __restrict__ dinv,
              float* __restrict__ m, int N, int c0) {
    int lane = threadIdx.x & 63;
    int nl = blockIdx.x * 4 + (threadIdx.x >> 6);
    int n = c0 + nl;
    u32 beg = (u32)rfl((int)offsets[n]);
    u32 end = (u32)rfl((int)offsets[n + 1]);
    float hv = h[((size_t)n << 6) + lane];
    float d0 = dinv[n],         d1 = dinv[N + n],     d2 = dinv[2 * N + n];
    float d3 = dinv[3 * N + n], d4 = dinv[4 * N + n], d5 = dinv[5 * N + n];
    float d6 = dinv[6 * N + n];
    float a0 = d0 * hv, a1 = d1 * hv, a2 = d2 * hv, a3 = d3 * hv;
    float a4 = d4 * hv, a5 = d5 * hv, a6 = d6 * hv;
    for (u32 base = beg; base < end; base += 64) {
        u32 rem = end - base;
        u32 e = 0; float dsv = 0.f;
        if ((u32)lane < rem) {
            e = entries[base + lane];
            dsv = dinv[(e >> 18) * N + (e & 0x3FFFFu)];
        }
        int cnt = (rem < 64u) ? (int)rem : 64;
        for (int j = 0; j < cnt; ++j) {
            u32 pk = (u32)__builtin_amdgcn_readlane((int)e, j);
            float cf = rlane_f(dsv, j);
            u32 src = pk & 0x3FFFFu;
            u32 k = pk >> 18;
            float hval = h[((size_t)src << 6) + lane];
            float c0s = (k == 0) ? cf : 0.f;
            float c1s = (k == 1) ? cf : 0.f;
            float c2s = (k == 2) ? cf : 0.f;
            float c3s = (k == 3) ? cf : 0.f;
            float c4s = (k == 4) ? cf : 0.f;
            float c5s = (k == 5) ? cf : 0.f;
            float c6s = (k == 6) ? cf : 0.f;
            a0 = fmaf(c0s, hval, a0);
            a1 = fmaf(c1s, hval, a1);
            a2 = fmaf(c2s, hval, a2);
            a3 = fmaf(c3s, hval, a3);
            a4 = fmaf(c4s, hval, a4);
            a5 = fmaf(c5s, hval, a5);
            a6 = fmaf(c6s, hval, a6);
        }
    }
    float* mp = m + (size_t)nl * 448 + lane;
    mp[0]   = d0 * a0; mp[64]  = d1 * a1; mp[128] = d2 * a2; mp[192] = d3 * a3;
    mp[256] = d4 * a4; mp[320] = d5 * a5; mp[384] = d6 * a6;
}

// ---------------- stacked GEMM [64,448]x[448,64] per block + bias + relu ----------------
__global__ __launch_bounds__(256)
void k_gemm(const float* __restrict__ m, Ptr7 W, const float* __restrict__ bsum,
            float* __restrict__ hout, int c0) {
    __shared__ float a[64 * 65];
    int tid = threadIdx.x;
    int nbl = blockIdx.x << 6;
    int r0 = (tid >> 4) << 2, q0 = (tid & 15) << 2;
    float acc[4][4] = {};
    for (int k = 0; k < 7; k++) {
        __syncthreads();
        const float* msrc = m + (size_t)nbl * 448 + k * 64;
#pragma unroll
        for (int rep = 0; rep < 16; rep++) {
            int idx = (rep << 8) + tid;
            int nn = idx >> 6, j = idx & 63;
            a[nn * 65 + j] = msrc[(size_t)nn * 448 + j];
        }
        __syncthreads();
        const float* Wk = W.p[k];
#pragma unroll 4
        for (int j = 0; j < 64; j++) {
            float4 w4 = *(const float4*)(Wk + (j << 6) + q0);
            float av0 = a[(r0 + 0) * 65 + j];
            float av1 = a[(r0 + 1) * 65 + j];
            float av2 = a[(r0 + 2) * 65 + j];
            float av3 = a[(r0 + 3) * 65 + j];
            acc[0][0] += av0 * w4.x; acc[0][1] += av0 * w4.y; acc[0][2] += av0 * w4.z; acc[0][3] += av0 * w4.w;
            acc[1][0] += av1 * w4.x; acc[1][1] += av1 * w4.y; acc[1][2] += av1 * w4.z; acc[1][3] += av1 * w4.w;
            acc[2][0] += av2 * w4.x; acc[2][1] += av2 * w4.y; acc[2][2] += av2 * w4.z; acc[2][3] += av2 * w4.w;
            acc[3][0] += av3 * w4.x; acc[3][1] += av3 * w4.y; acc[3][2] += av3 * w4.z; acc[3][3] += av3 * w4.w;
        }
    }
    float4 b4 = *(const float4*)(bsum + q0);
#pragma unroll
    for (int rr = 0; rr < 4; rr++) {
        float4 o;
        o.x = fmaxf(acc[rr][0] + b4.x, 0.f);
        o.y = fmaxf(acc[rr][1] + b4.y, 0.f);
        o.z = fmaxf(acc[rr][2] + b4.z, 0.f);
        o.w = fmaxf(acc[rr][3] + b4.w, 0.f);
        *(float4*)(hout + (size_t)(c0 + nbl + r0 + rr) * 64 + q0) = o;
    }
}

// ---------------- pooling + 2-layer MLP head ----------------
__global__ __launch_bounds__(256)
void k_head(const float* __restrict__ h, const float* __restrict__ w1,
            const float* __restrict__ b1, const float* __restrict__ w2,
            const float* __restrict__ b2, float* __restrict__ out) {
    __shared__ float gmax[4][64];
    __shared__ float gl[64];
    __shared__ float t1p[4][64];
    int b = blockIdx.x;
    int tid = threadIdx.x;
    int d = tid & 63, rg = tid >> 6;
    const float* hb = h + (size_t)b * 64 * 64;
    float pm = -1e30f;
#pragma unroll
    for (int i = 0; i < 16; i++) pm = fmaxf(pm, hb[(rg * 16 + i) * 64 + d]);
    gmax[rg][d] = pm; __syncthreads();
    if (rg == 0) gl[d] = fmaxf(fmaxf(gmax[0][d], gmax[1][d]), fmaxf(gmax[2][d], gmax[3][d]));
    __syncthreads();
    float s = 0.f;
#pragma unroll
    for (int i = 0; i < 16; i++) { int dd = rg * 16 + i; s += gl[dd] * w1[dd * 64 + d]; }
    t1p[rg][d] = s; __syncthreads();
    if (rg == 0) {
        float t1 = fmaxf(t1p[0][d] + t1p[1][d] + t1p[2][d] + t1p[3][d] + b1[d], 0.f);
        float v = t1 * w2[d];
        for (int off = 32; off; off >>= 1) v += __shfl_down(v, off, 64);
        if (d == 0) out[b] = v + b2[0];
    }
}

extern "C" void kernel_launch(void* const* d_in, const int* in_sizes, int n_in,
                              void* d_out, int out_size, void* d_ws, size_t ws_size,
                              hipStream_t stream) {
    const float* x     = (const float*)d_in[0];
    const int*   ei    = (const int*)d_in[1];
    const int*   ty    = (const int*)d_in[2];
    const float* nodeW = (const float*)d_in[3];
    const float* nodeb = (const float*)d_in[4];
    const float* out1W = (const float*)d_in[5];
    const float* out1b = (const float*)d_in[6];
    const float* out2W = (const float*)d_in[7];
    const float* out2b = (const float*)d_in[8];

    Ptr7 W, B;
    W.p[0] = (const float*)d_in[9];  B.p[0] = (const float*)d_in[10];   // W1
    W.p[1] = (const float*)d_in[11]; B.p[1] = (const float*)d_in[12];   // W2
    W.p[2] = (const float*)d_in[13]; B.p[2] = (const float*)d_in[14];   // W3
    W.p[3] = (const float*)d_in[15]; B.p[3] = (const float*)d_in[16];   // W4
    W.p[4] = (const float*)d_in[17]; B.p[4] = (const float*)d_in[18];   // W2b
    W.p[5] = (const float*)d_in[19]; B.p[5] = (const float*)d_in[20];   // W3b
    W.p[6] = (const float*)d_in[21]; B.p[6] = (const float*)d_in[22];   // W4b

    const int N = in_sizes[0];       // 262144
    const int E = in_sizes[2];       // 4194304

    char* p = (char*)d_ws;
    auto carve = [&](size_t bytes) { void* r = (void*)p; p += (bytes + 255) & ~(size_t)255; return r; };
    float* hA       = (float*)carve((size_t)N * 64 * 4);
    float* hB       = (float*)carve((size_t)N * 64 * 4);
    u32*   entries  = (u32*)carve((size_t)2 * E * 4);
    float* dinv     = (float*)carve((size_t)7 * N * 4);
    u32*   cnt      = (u32*)carve((size_t)N * 4);
    u32*   scanS    = (u32*)carve((size_t)N * 4);
    u32*   offsets  = (u32*)carve((size_t)(N + 1) * 4);
    float* P        = (float*)carve((size_t)N * 8 * 4);
    float* Q        = (float*)carve((size_t)N * 8 * 4);
    float* U        = (float*)carve(7 * 64 * 4);
    float* V        = (float*)carve(7 * 64 * 4);
    u32*   bsums    = (u32*)carve(1024);
    u32*   bexcl    = (u32*)carve(1024);
    float* bsum     = (float*)carve(256);
    u32*   bucketCnt  = (u32*)carve(256 * 4);
    u32*   bucketBase = (u32*)carve(257 * 4);
    u32*   gcursor    = (u32*)carve(256 * 4);
    size_t used = (size_t)(p - (char*)d_ws);
    size_t avail = (ws_size > used) ? (ws_size - used) : 0;
    // union region: tmpItems (2E u32, dead after passC) aliases m (chunk buffer)
    u32*   tmpItems = (u32*)p;
    float* m        = (float*)p;
    size_t tmpBytes = (size_t)2 * E * 4;
    size_t mAvail = (avail > tmpBytes) ? avail : tmpBytes;   // tmp must fit regardless
    size_t chunkNodes = (mAvail / (448 * 4)) & ~(size_t)63;
    if (chunkNodes < 64) chunkNodes = 64;
    if (chunkNodes > 32768) chunkNodes = 32768;              // keep m L3-resident
    if (chunkNodes > (size_t)N) chunkNodes = (size_t)N;
    if ((size_t)chunkNodes * 448 * 4 > avail && avail >= tmpBytes)
        chunkNodes = (avail / (448 * 4)) & ~(size_t)63;
    if (chunkNodes < 64) chunkNodes = 64;
    (void)n_in; (void)out_size;

    hipMemsetAsync(bucketCnt, 0, 256 * 4, stream);

    // ---- bucketed CSR build ----
    k_hist<<<2048, 256, 0, stream>>>(ei, ty, E, bucketCnt);
    k_bucket_scan<<<1, 256, 0, stream>>>(bucketCnt, bucketBase, gcursor);
    k_passA<<<(E + 4095) / 4096, 256, 0, stream>>>(ei, ty, E, gcursor, tmpItems);
    k_passB<<<256, 256, 0, stream>>>(tmpItems, bucketBase, dinv, cnt, N);

    int nScanBlocks = N / 1024;  // 256
    k_scan1<<<nScanBlocks, 256, 0, stream>>>(cnt, scanS, bsums);
    k_scan2<<<1, 256, 0, stream>>>(bsums, bexcl, nScanBlocks);
    k_scan3<<<nScanBlocks, 256, 0, stream>>>(scanS, cnt, bexcl, offsets);
    k_passC<<<256, 256, 0, stream>>>(tmpItems, bucketBase, offsets, entries);

    k_bsum<<<1, 64, 0, stream>>>(B, bsum);
    k_uv<<<7, 64, 0, stream>>>(nodeW, nodeb, W, U, V);

    // depth 1 via rank-2 shortcut
    k_gather1<<<N / 4, 256, 0, stream>>>(x, entries, offsets, dinv, N, P, Q);
    k_h1<<<(N * 64) / 256, 256, 0, stream>>>(P, Q, U, V, bsum, hA);

    // depths 2,3: full gather + GEMM, chunked (m aliases dead tmpItems)
    float* hcur = hA;
    float* hnext = hB;
    for (int depth = 0; depth < 2; depth++) {
        for (int c0 = 0; c0 < N; c0 += (int)chunkNodes) {
            int cn = (int)(((size_t)(N - c0) < chunkNodes) ? (size_t)(N - c0) : chunkNodes);
            k_gather<<<cn / 4, 256, 0, stream>>>(hcur, entries, offsets, dinv, m, N, c0);
            k_gemm<<<cn / 64, 256, 0, stream>>>(m, W, bsum, hnext, c0);
        }
        float* t = hcur; hcur = hnext; hnext = t;
    }

    k_head<<<N / 64, 256, 0, stream>>>(hcur, out1W, out1b, out2W, out2b, (float*)d_out);
}

// Round 5
// 1601.475 us; speedup vs baseline: 2.1150x; 1.3432x over previous
//
#include <hip/hip_runtime.h>
#include <stdint.h>

typedef unsigned int u32;
typedef unsigned short u16;
typedef __attribute__((ext_vector_type(8))) short bf16x8;
typedef __attribute__((ext_vector_type(4))) float f32x4;

struct Ptr7 { const float* p[7]; };

__device__ __forceinline__ int rfl(int v) { return __builtin_amdgcn_readfirstlane(v); }
__device__ __forceinline__ float rlane_f(float v, int j) {
    return __int_as_float(__builtin_amdgcn_readlane(__float_as_int(v), j));
}
__device__ __forceinline__ u16 f2bf(float f) {
    u32 u = __float_as_uint(f);
    u32 r = (u + 0x7FFFu + ((u >> 16) & 1u)) >> 16;
    return (u16)r;
}
__device__ __forceinline__ float bf2f(u16 h) { return __uint_as_float((u32)h << 16); }

// ================= bucketed CSR build =================
// item = src(18b) | k(3b)<<18 | dstlocal(10b)<<21 ; bucket = target >> 10

__global__ __launch_bounds__(256)
void k_hist(const int* __restrict__ ei, const int* __restrict__ ty, int E,
            u32* __restrict__ bucketCnt) {
    __shared__ u32 hist[256];
    int tid = threadIdx.x;
    hist[tid] = 0;
    __syncthreads();
    for (int e = blockIdx.x * 256 + tid; e < E; e += gridDim.x * 256) {
        int s = ei[e], d = ei[E + e], t = ty[e];
        if (t >= 1) atomicAdd(&hist[(u32)d >> 10], 1u);
        if (t >= 2) atomicAdd(&hist[(u32)s >> 10], 1u);
    }
    __syncthreads();
    if (hist[tid]) atomicAdd(&bucketCnt[tid], hist[tid]);
}

__global__ void k_bucket_scan(const u32* __restrict__ bucketCnt,
                              u32* __restrict__ bucketBase, u32* __restrict__ gcursor) {
    __shared__ u32 wsum[4];
    int tid = threadIdx.x;
    u32 v = bucketCnt[tid];
    u32 sc = v;
    for (int off = 1; off < 64; off <<= 1) {
        u32 t2 = __shfl_up(sc, off, 64);
        if ((tid & 63) >= off) sc += t2;
    }
    if ((tid & 63) == 63) wsum[tid >> 6] = sc;
    __syncthreads();
    u32 wadd = 0;
    int w = tid >> 6;
    if (w > 0) wadd += wsum[0];
    if (w > 1) wadd += wsum[1];
    if (w > 2) wadd += wsum[2];
    u32 incl = sc + wadd;
    u32 excl = incl - v;
    bucketBase[tid] = excl;
    gcursor[tid] = excl;
    if (tid == 255) bucketBase[256] = incl;
}

__global__ __launch_bounds__(256)
void k_passA(const int* __restrict__ ei, const int* __restrict__ ty, int E,
             u32* __restrict__ gcursor, u32* __restrict__ tmpItems) {
    __shared__ u32 hist[256], gb[256], cur[256];
    int tid = threadIdx.x;
    int e0 = blockIdx.x * 4096;
    hist[tid] = 0;
    __syncthreads();
#pragma unroll
    for (int i = 0; i < 16; i++) {
        int e = e0 + i * 256 + tid;
        if (e < E) {
            int s = ei[e], d = ei[E + e], t = ty[e];
            if (t >= 1) atomicAdd(&hist[(u32)d >> 10], 1u);
            if (t >= 2) atomicAdd(&hist[(u32)s >> 10], 1u);
        }
    }
    __syncthreads();
    u32 h = hist[tid];
    gb[tid] = h ? atomicAdd(&gcursor[tid], h) : 0u;
    cur[tid] = 0;
    __syncthreads();
#pragma unroll
    for (int i = 0; i < 16; i++) {
        int e = e0 + i * 256 + tid;
        if (e < E) {
            int s = ei[e], d = ei[E + e], t = ty[e];
            if (t >= 1) {
                u32 b = (u32)d >> 10;
                u32 slot = atomicAdd(&cur[b], 1u);
                tmpItems[gb[b] + slot] = (u32)s | ((u32)(t - 1) << 18) | (((u32)d & 1023u) << 21);
            }
            if (t >= 2) {
                u32 b = (u32)s >> 10;
                u32 slot = atomicAdd(&cur[b], 1u);
                tmpItems[gb[b] + slot] = (u32)d | ((u32)(t + 2) << 18) | (((u32)s & 1023u) << 21);
            }
        }
    }
}

// ---- passB: per-(node,k) degree counts -> dinv + kcnt[8N] ----
__global__ __launch_bounds__(256)
void k_passB(const u32* __restrict__ tmpItems, const u32* __restrict__ bucketBase,
             float* __restrict__ dinv, u32* __restrict__ kcnt, int N) {
    __shared__ u32 c[1024 * 8];
    int b = blockIdx.x, tid = threadIdx.x;
    for (int i = tid; i < 8192; i += 256) c[i] = 0;
    __syncthreads();
    u32 beg = bucketBase[b], end = bucketBase[b + 1];
    for (u32 i = beg + tid; i < end; i += 256) {
        u32 it = tmpItems[i];
        atomicAdd(&c[(it >> 21) * 8 + ((it >> 18) & 7)], 1u);
    }
    __syncthreads();
    int nodeBase = b << 10;
    for (int i = tid; i < 8192; i += 256) kcnt[(size_t)b * 8192 + i] = c[i];
    for (int l = tid; l < 1024; l += 256) {
        int n = nodeBase + l;
#pragma unroll
        for (int k = 0; k < 7; k++)
            dinv[k * N + n] = rsqrtf(1.0f + (float)c[l * 8 + k]);
    }
}

// ---------------- scan over 8N elems, 8192/block, 256 blocks ----------------
__global__ __launch_bounds__(256)
void k_scan1(const u32* __restrict__ kcnt, u32* __restrict__ kofs, u32* __restrict__ bsums) {
    __shared__ u32 lds[256];
    int t = threadIdx.x;
    size_t base = (size_t)blockIdx.x * 8192 + (size_t)t * 32;
    u32 v[32];
    u32 s = 0;
    const uint4* src = (const uint4*)(kcnt + base);
#pragma unroll
    for (int q = 0; q < 8; q++) {
        uint4 c4 = src[q];
        v[q * 4 + 0] = s; s += c4.x;
        v[q * 4 + 1] = s; s += c4.y;
        v[q * 4 + 2] = s; s += c4.z;
        v[q * 4 + 3] = s; s += c4.w;
    }
    lds[t] = s; __syncthreads();
    for (int off = 1; off < 256; off <<= 1) {
        u32 x2 = (t >= off) ? lds[t - off] : 0u;
        __syncthreads();
        lds[t] += x2;
        __syncthreads();
    }
    u32 texcl = lds[t] - s;
    uint4* dst = (uint4*)(kofs + base);
#pragma unroll
    for (int q = 0; q < 8; q++) {
        uint4 o;
        o.x = v[q * 4 + 0] + texcl; o.y = v[q * 4 + 1] + texcl;
        o.z = v[q * 4 + 2] + texcl; o.w = v[q * 4 + 3] + texcl;
        dst[q] = o;
    }
    if (t == 255) bsums[blockIdx.x] = lds[255];
}

__global__ void k_scan2(const u32* __restrict__ bsums, u32* __restrict__ bexcl, int nb) {
    __shared__ u32 lds[256];
    int t = threadIdx.x;
    u32 v = (t < nb) ? bsums[t] : 0u;
    lds[t] = v; __syncthreads();
    for (int off = 1; off < 256; off <<= 1) {
        u32 x2 = (t >= off) ? lds[t - off] : 0u;
        __syncthreads();
        lds[t] += x2;
        __syncthreads();
    }
    if (t < nb) bexcl[t] = lds[t] - v;
}

__global__ __launch_bounds__(256)
void k_scan3(u32* __restrict__ kofs, const u32* __restrict__ bexcl,
             const u32* __restrict__ bsums, u32 M) {
    int t = threadIdx.x;
    size_t base = (size_t)blockIdx.x * 8192 + (size_t)t * 32;
    u32 add = bexcl[blockIdx.x];
    uint4* p4 = (uint4*)(kofs + base);
#pragma unroll
    for (int q = 0; q < 8; q++) {
        uint4 o = p4[q];
        o.x += add; o.y += add; o.z += add; o.w += add;
        p4[q] = o;
    }
    if (blockIdx.x == 255 && t == 255) kofs[M] = add + bsums[255];
}

// ---- passC: scatter into final CSR (k-sorted within node) + coef ----
__global__ __launch_bounds__(256)
void k_passC(const u32* __restrict__ tmpItems, const u32* __restrict__ bucketBase,
             const u32* __restrict__ kofs, const float* __restrict__ dinv,
             u32* __restrict__ entries, float* __restrict__ coef, int N) {
    __shared__ u32 cur[8192];
    int b = blockIdx.x, tid = threadIdx.x;
    for (int i = tid; i < 8192; i += 256) cur[i] = kofs[(size_t)b * 8192 + i];
    __syncthreads();
    u32 beg = bucketBase[b], end = bucketBase[b + 1];
    for (u32 i = beg + tid; i < end; i += 256) {
        u32 it = tmpItems[i];
        u32 k = (it >> 18) & 7u;
        u32 src = it & 0x3FFFFu;
        u32 p = atomicAdd(&cur[(it >> 21) * 8 + k], 1u);
        entries[p] = it & 0x1FFFFFu;
        coef[p] = dinv[k * N + src];
    }
}

// ================= small prep kernels =================
__global__ void k_bsum(Ptr7 b, float* __restrict__ bsum) {
    int d = threadIdx.x;
    float s = 0.f;
#pragma unroll
    for (int k = 0; k < 7; k++) s += b.p[k][d];
    bsum[d] = s;
}

__global__ void k_uv(const float* __restrict__ nW, const float* __restrict__ nb,
                     Ptr7 W, float* __restrict__ U, float* __restrict__ V) {
    int k = blockIdx.x, d = threadIdx.x;
    const float* Wk = W.p[k];
    float u = 0.f, v = 0.f;
#pragma unroll 8
    for (int j = 0; j < 64; j++) {
        float w = Wk[j * 64 + d];
        u += nW[j] * w;
        v += nb[j] * w;
    }
    U[k * 64 + d] = u;
    V[k * 64 + d] = v;
}

// pack W into MFMA B-fragment order: Wp[((k*2+ks)*4+ct)*512 + l*8 + i]
//   = W_k[ks*32 + (l>>4)*8 + i][ct*16 + (l&15)]
__global__ void k_packW(Ptr7 W, u16* __restrict__ Wp) {
    int k = blockIdx.x;
    int tid = threadIdx.x;                 // 512 threads
    int ks = tid >> 8, ct = (tid >> 6) & 3, l = tid & 63;
    const float* Wk = W.p[k];
    u16* dst = Wp + (((size_t)(k * 2 + ks) * 4 + ct) * 512 + l * 8);
    int row0 = ks * 32 + (l >> 4) * 8;
    int col = ct * 16 + (l & 15);
#pragma unroll
    for (int i = 0; i < 8; i++) dst[i] = f2bf(Wk[(row0 + i) * 64 + col]);
}

// ---------------- depth-1 light gather (entries+coef linear, x scattered) ----------------
__global__ __launch_bounds__(256)
void k_gather1(const float* __restrict__ x, const u32* __restrict__ entries,
               const float* __restrict__ coef, const u32* __restrict__ kofs,
               const float* __restrict__ dinv, int N,
               float* __restrict__ P, float* __restrict__ Q) {
    int lane = threadIdx.x & 63;
    int n = blockIdx.x * 4 + (threadIdx.x >> 6);
    u32 beg = (u32)rfl((int)kofs[(size_t)n << 3]);
    u32 end = (u32)rfl((int)kofs[((size_t)n << 3) + 7]);
    float sa0 = 0, sa1 = 0, sa2 = 0, sa3 = 0, sa4 = 0, sa5 = 0, sa6 = 0;
    float sc0 = 0, sc1 = 0, sc2 = 0, sc3 = 0, sc4 = 0, sc5 = 0, sc6 = 0;
    for (u32 base = beg; base < end; base += 64) {
        u32 rem = end - base;
        if ((u32)lane < rem) {
            u32 e = entries[base + lane];
            float cf = coef[base + lane];
            u32 src = e & 0x3FFFFu;
            u32 k = e >> 18;
            float val = cf * x[src];
            sa0 += (k == 0) ? val : 0.f; sc0 += (k == 0) ? cf : 0.f;
            sa1 += (k == 1) ? val : 0.f; sc1 += (k == 1) ? cf : 0.f;
            sa2 += (k == 2) ? val : 0.f; sc2 += (k == 2) ? cf : 0.f;
            sa3 += (k == 3) ? val : 0.f; sc3 += (k == 3) ? cf : 0.f;
            sa4 += (k == 4) ? val : 0.f; sc4 += (k == 4) ? cf : 0.f;
            sa5 += (k == 5) ? val : 0.f; sc5 += (k == 5) ? cf : 0.f;
            sa6 += (k == 6) ? val : 0.f; sc6 += (k == 6) ? cf : 0.f;
        }
    }
#pragma unroll
    for (int off = 1; off < 64; off <<= 1) {
        sa0 += __shfl_xor(sa0, off, 64); sc0 += __shfl_xor(sc0, off, 64);
        sa1 += __shfl_xor(sa1, off, 64); sc1 += __shfl_xor(sc1, off, 64);
        sa2 += __shfl_xor(sa2, off, 64); sc2 += __shfl_xor(sc2, off, 64);
        sa3 += __shfl_xor(sa3, off, 64); sc3 += __shfl_xor(sc3, off, 64);
        sa4 += __shfl_xor(sa4, off, 64); sc4 += __shfl_xor(sc4, off, 64);
        sa5 += __shfl_xor(sa5, off, 64); sc5 += __shfl_xor(sc5, off, 64);
        sa6 += __shfl_xor(sa6, off, 64); sc6 += __shfl_xor(sc6, off, 64);
    }
    if (lane < 7) {
        float sa = (lane == 0) ? sa0 : (lane == 1) ? sa1 : (lane == 2) ? sa2 :
                   (lane == 3) ? sa3 : (lane == 4) ? sa4 : (lane == 5) ? sa5 : sa6;
        float sc = (lane == 0) ? sc0 : (lane == 1) ? sc1 : (lane == 2) ? sc2 :
                   (lane == 3) ? sc3 : (lane == 4) ? sc4 : (lane == 5) ? sc5 : sc6;
        float dn = dinv[lane * N + n];
        float xn = x[n];
        P[n * 8 + lane] = dn * (sa + dn * xn);
        Q[n * 8 + lane] = dn * (sc + dn);
    }
}

// ---------------- h1 = relu(P@U + Q@V + bsum) -> bf16 ----------------
__global__ __launch_bounds__(256)
void k_h1(const float* __restrict__ P, const float* __restrict__ Q,
          const float* __restrict__ U, const float* __restrict__ V,
          const float* __restrict__ bsum, u16* __restrict__ h1) {
    int i = blockIdx.x * 256 + threadIdx.x;
    int n = rfl(i >> 6);
    int d = i & 63;
    float acc = bsum[d];
#pragma unroll
    for (int k = 0; k < 7; k++)
        acc += P[n * 8 + k] * U[k * 64 + d] + Q[n * 8 + k] * V[k * 64 + d];
    h1[((size_t)n << 6) + d] = f2bf(fmaxf(acc, 0.f));
}

// ---------------- full gather (depths 2,3): bf16 h rows, k-sorted entries ----------------
__global__ __launch_bounds__(256)
void k_gather(const u16* __restrict__ h, const u32* __restrict__ entries,
              const float* __restrict__ coef, const u32* __restrict__ kofs,
              const float* __restrict__ dinv, u16* __restrict__ m, int N, int c0) {
    int lane = threadIdx.x & 63;
    int nl = blockIdx.x * 4 + (threadIdx.x >> 6);
    int n = c0 + nl;
    u32 beg = (u32)rfl((int)kofs[(size_t)n << 3]);
    u32 end = (u32)rfl((int)kofs[((size_t)n << 3) + 7]);
    float hv = bf2f(h[((size_t)n << 6) + lane]);
    float d0 = dinv[n],         d1 = dinv[N + n],     d2 = dinv[2 * N + n];
    float d3 = dinv[3 * N + n], d4 = dinv[4 * N + n], d5 = dinv[5 * N + n];
    float d6 = dinv[6 * N + n];
    float a0 = d0 * hv, a1 = d1 * hv, a2 = d2 * hv, a3 = d3 * hv;
    float a4 = d4 * hv, a5 = d5 * hv, a6 = d6 * hv;
    for (u32 base = beg; base < end; base += 64) {
        u32 rem = end - base;
        u32 e = 0; float cfv = 0.f;
        if ((u32)lane < rem) {
            e = entries[base + lane];
            cfv = coef[base + lane];
        }
        int cnt = (rem < 64u) ? (int)rem : 64;
        for (int j = 0; j < cnt; ++j) {
            u32 pk = (u32)__builtin_amdgcn_readlane((int)e, j);
            float cf = rlane_f(cfv, j);
            u32 src = pk & 0x3FFFFu;
            u32 k = pk >> 18;     // wave-uniform scalar (k-sorted runs)
            float hval = bf2f(h[((size_t)src << 6) + lane]);
            switch (k) {
                case 0: a0 = fmaf(cf, hval, a0); break;
                case 1: a1 = fmaf(cf, hval, a1); break;
                case 2: a2 = fmaf(cf, hval, a2); break;
                case 3: a3 = fmaf(cf, hval, a3); break;
                case 4: a4 = fmaf(cf, hval, a4); break;
                case 5: a5 = fmaf(cf, hval, a5); break;
                default: a6 = fmaf(cf, hval, a6); break;
            }
        }
    }
    u16* mp = m + (size_t)nl * 448 + lane;
    mp[0]   = f2bf(d0 * a0); mp[64]  = f2bf(d1 * a1); mp[128] = f2bf(d2 * a2);
    mp[192] = f2bf(d3 * a3); mp[256] = f2bf(d4 * a4); mp[320] = f2bf(d5 * a5);
    mp[384] = f2bf(d6 * a6);
}

// ---------------- MFMA GEMM: [64,448]x[448,64] per block + bias + relu ----------------
__global__ __launch_bounds__(256)
void k_gemm(const u16* __restrict__ m, const u16* __restrict__ Wp,
            const float* __restrict__ bsum, u16* __restrict__ hout, int c0) {
    int tid = threadIdx.x;
    int w = tid >> 6, l = tid & 63;
    int nb = blockIdx.x << 6;                            // chunk-local node base
    const u16* arow = m + (size_t)(nb + (w << 4) + (l & 15)) * 448 + ((l >> 4) << 3);
    const u16* bp = Wp + (size_t)l * 8;
    f32x4 acc0 = {0,0,0,0}, acc1 = {0,0,0,0}, acc2 = {0,0,0,0}, acc3 = {0,0,0,0};
#pragma unroll
    for (int kk = 0; kk < 14; kk++) {
        bf16x8 a  = *(const bf16x8*)(arow + kk * 32);
        bf16x8 b0 = *(const bf16x8*)(bp + (size_t)(kk * 4 + 0) * 512);
        bf16x8 b1 = *(const bf16x8*)(bp + (size_t)(kk * 4 + 1) * 512);
        bf16x8 b2 = *(const bf16x8*)(bp + (size_t)(kk * 4 + 2) * 512);
        bf16x8 b3 = *(const bf16x8*)(bp + (size_t)(kk * 4 + 3) * 512);
        acc0 = __builtin_amdgcn_mfma_f32_16x16x32_bf16(a, b0, acc0, 0, 0, 0);
        acc1 = __builtin_amdgcn_mfma_f32_16x16x32_bf16(a, b1, acc1, 0, 0, 0);
        acc2 = __builtin_amdgcn_mfma_f32_16x16x32_bf16(a, b2, acc2, 0, 0, 0);
        acc3 = __builtin_amdgcn_mfma_f32_16x16x32_bf16(a, b3, acc3, 0, 0, 0);
    }
    int rl = (l >> 4) << 2, cl = l & 15;
    int rowg = c0 + nb + (w << 4) + rl;
    f32x4 accs[4] = {acc0, acc1, acc2, acc3};
#pragma unroll
    for (int ct = 0; ct < 4; ct++) {
        int col = ct * 16 + cl;
        float bv = bsum[col];
#pragma unroll
        for (int reg = 0; reg < 4; reg++) {
            float vv = fmaxf(accs[ct][reg] + bv, 0.f);
            hout[(size_t)(rowg + reg) * 64 + col] = f2bf(vv);
        }
    }
}

// ---------------- pooling + 2-layer MLP head (bf16 h) ----------------
__global__ __launch_bounds__(256)
void k_head(const u16* __restrict__ h, const float* __restrict__ w1,
            const float* __restrict__ b1, const float* __restrict__ w2,
            const float* __restrict__ b2, float* __restrict__ out) {
    __shared__ float gmax[4][64];
    __shared__ float gl[64];
    __shared__ float t1p[4][64];
    int b = blockIdx.x;
    int tid = threadIdx.x;
    int d = tid & 63, rg = tid >> 6;
    const u16* hb = h + (size_t)b * 64 * 64;
    float pm = -1e30f;
#pragma unroll
    for (int i = 0; i < 16; i++) pm = fmaxf(pm, bf2f(hb[(rg * 16 + i) * 64 + d]));
    gmax[rg][d] = pm; __syncthreads();
    if (rg == 0) gl[d] = fmaxf(fmaxf(gmax[0][d], gmax[1][d]), fmaxf(gmax[2][d], gmax[3][d]));
    __syncthreads();
    float s = 0.f;
#pragma unroll
    for (int i = 0; i < 16; i++) { int dd = rg * 16 + i; s += gl[dd] * w1[dd * 64 + d]; }
    t1p[rg][d] = s; __syncthreads();
    if (rg == 0) {
        float t1 = fmaxf(t1p[0][d] + t1p[1][d] + t1p[2][d] + t1p[3][d] + b1[d], 0.f);
        float v = t1 * w2[d];
        for (int off = 32; off; off >>= 1) v += __shfl_down(v, off, 64);
        if (d == 0) out[b] = v + b2[0];
    }
}

extern "C" void kernel_launch(void* const* d_in, const int* in_sizes, int n_in,
                              void* d_out, int out_size, void* d_ws, size_t ws_size,
                              hipStream_t stream) {
    const float* x     = (const float*)d_in[0];
    const int*   ei    = (const int*)d_in[1];
    const int*   ty    = (const int*)d_in[2];
    const float* nodeW = (const float*)d_in[3];
    const float* nodeb = (const float*)d_in[4];
    const float* out1W = (const float*)d_in[5];
    const float* out1b = (const float*)d_in[6];
    const float* out2W = (const float*)d_in[7];
    const float* out2b = (const float*)d_in[8];

    Ptr7 W, B;
    W.p[0] = (const float*)d_in[9];  B.p[0] = (const float*)d_in[10];   // W1
    W.p[1] = (const float*)d_in[11]; B.p[1] = (const float*)d_in[12];   // W2
    W.p[2] = (const float*)d_in[13]; B.p[2] = (const float*)d_in[14];   // W3
    W.p[3] = (const float*)d_in[15]; B.p[3] = (const float*)d_in[16];   // W4
    W.p[4] = (const float*)d_in[17]; B.p[4] = (const float*)d_in[18];   // W2b
    W.p[5] = (const float*)d_in[19]; B.p[5] = (const float*)d_in[20];   // W3b
    W.p[6] = (const float*)d_in[21]; B.p[6] = (const float*)d_in[22];   // W4b

    const int N = in_sizes[0];       // 262144
    const int E = in_sizes[2];       // 4194304

    char* p = (char*)d_ws;
    auto carve = [&](size_t bytes) { void* r = (void*)p; p += (bytes + 255) & ~(size_t)255; return r; };
    u16*   hA       = (u16*)carve((size_t)N * 64 * 2);
    u16*   hB       = (u16*)carve((size_t)N * 64 * 2);
    u32*   entries  = (u32*)carve((size_t)2 * E * 4);
    float* coef     = (float*)carve((size_t)2 * E * 4);
    float* dinv     = (float*)carve((size_t)7 * N * 4);
    u32*   kcnt     = (u32*)carve((size_t)8 * N * 4);
    u32*   kofs     = (u32*)carve(((size_t)8 * N + 1) * 4);
    float* P        = (float*)carve((size_t)N * 8 * 4);
    float* Q        = (float*)carve((size_t)N * 8 * 4);
    float* U        = (float*)carve(7 * 64 * 4);
    float* V        = (float*)carve(7 * 64 * 4);
    float* bsum     = (float*)carve(256);
    u16*   Wp       = (u16*)carve((size_t)7 * 2 * 4 * 512 * 2);
    u32*   bucketCnt  = (u32*)carve(256 * 4);
    u32*   bucketBase = (u32*)carve(257 * 4);
    u32*   gcursor    = (u32*)carve(256 * 4);
    u32*   bsums      = (u32*)carve(1024);
    u32*   bexcl      = (u32*)carve(1024);
    size_t used = (size_t)(p - (char*)d_ws);
    size_t avail = (ws_size > used) ? (ws_size - used) : 0;
    // union region: tmpItems (2E u32, dead after passC) aliases m (bf16 chunk)
    u32*   tmpItems = (u32*)p;
    u16*   m        = (u16*)p;
    size_t chunkNodes = (avail / (448 * 2)) & ~(size_t)63;
    if (chunkNodes < 64) chunkNodes = 64;
    if (chunkNodes > 65536) chunkNodes = 65536;
    if (chunkNodes > (size_t)N) chunkNodes = (size_t)N;
    (void)n_in; (void)out_size;

    hipMemsetAsync(bucketCnt, 0, 256 * 4, stream);

    // ---- bucketed CSR build (k-sorted entries + linear coef) ----
    k_hist<<<2048, 256, 0, stream>>>(ei, ty, E, bucketCnt);
    k_bucket_scan<<<1, 256, 0, stream>>>(bucketCnt, bucketBase, gcursor);
    k_passA<<<(E + 4095) / 4096, 256, 0, stream>>>(ei, ty, E, gcursor, tmpItems);
    k_passB<<<256, 256, 0, stream>>>(tmpItems, bucketBase, dinv, kcnt, N);
    k_scan1<<<256, 256, 0, stream>>>(kcnt, kofs, bsums);
    k_scan2<<<1, 256, 0, stream>>>(bsums, bexcl, 256);
    k_scan3<<<256, 256, 0, stream>>>(kofs, bexcl, bsums, (u32)8 * N);
    k_passC<<<256, 256, 0, stream>>>(tmpItems, bucketBase, kofs, dinv, entries, coef, N);

    k_bsum<<<1, 64, 0, stream>>>(B, bsum);
    k_uv<<<7, 64, 0, stream>>>(nodeW, nodeb, W, U, V);
    k_packW<<<7, 512, 0, stream>>>(W, Wp);

    // depth 1 via rank-2 shortcut
    k_gather1<<<N / 4, 256, 0, stream>>>(x, entries, coef, kofs, dinv, N, P, Q);
    k_h1<<<(N * 64) / 256, 256, 0, stream>>>(P, Q, U, V, bsum, hA);

    // depths 2,3: full gather + MFMA GEMM, chunked (m aliases dead tmpItems)
    u16* hcur = hA;
    u16* hnext = hB;
    for (int depth = 0; depth < 2; depth++) {
        for (int c0 = 0; c0 < N; c0 += (int)chunkNodes) {
            int cn = (int)(((size_t)(N - c0) < chunkNodes) ? (size_t)(N - c0) : chunkNodes);
            k_gather<<<cn / 4, 256, 0, stream>>>(hcur, entries, coef, kofs, dinv, m, N, c0);
            k_gemm<<<cn / 64, 256, 0, stream>>>(m, Wp, bsum, hnext, c0);
        }
        u16* t = hcur; hcur = hnext; hnext = t;
    }

    k_head<<<N / 64, 256, 0, stream>>>(hcur, out1W, out1b, out2W, out2b, (float*)d_out);
}